// Round 11
// baseline (49.077 us; speedup 1.0000x reference)
//
#include <hip/hip_runtime.h>

static constexpr int    N      = 2048;
static constexpr int    NBLK   = 256;
static constexpr int    NTHR   = 1024;
static constexpr int    RPB    = 8;     // rows (or cols) per block
static constexpr double D_MASS = 0.9;
static constexpr double D_TOL  = 0.01;
static constexpr int    NITER  = 50;

struct Ws {
    double a_sum, b_sum;
    double bandSum[NBLK];                // sum K0 over band
    double s2Band[NBLK];                 // sum K0^2 over band
    double rowSum[N];
    double dotParts[NBLK], errAParts[NBLK], errBParts[NBLK];
    float  U[N], V[N];
    // fallback-only double state (single-block path; never touched on fast path)
    double Ud[N], rpD[N], Vd[N], cpD[N], UpD[N], VpD[N];
    float  partialT[(size_t)N * NBLK];   // [col][srcblk], 2 MB
    float  partialG[(size_t)N * NBLK];   // U * K0^2
    float  partialH[(size_t)N * NBLK];   // U^2 * K0^2
};

// deterministic all-thread block reduction (1024 threads, 16 waves)
__device__ __forceinline__ double block_reduce(double v, double* s16) {
    for (int off = 32; off; off >>= 1) v += __shfl_xor(v, off, 64);
    const int wave = threadIdx.x >> 6, lane = threadIdx.x & 63;
    __syncthreads();
    if (lane == 0) s16[wave] = v;
    __syncthreads();
    double s = 0.0;
    #pragma unroll
    for (int w = 0; w < 16; ++w) s += s16[w];
    return s;
}

// ---- K1: row sums + band sums of K0 and K0^2, a/b sums ----
__global__ void __launch_bounds__(NTHR)
k1_sums(const float* __restrict__ C, const float* __restrict__ a,
        const float* __restrict__ b, Ws* __restrict__ ws)
{
    __shared__ double s16[16];
    const int tid = threadIdx.x, bid = blockIdx.x, lane = tid & 63;
    const int r0 = bid * RPB, rloc = tid >> 7, cgrp = tid & 127;

    if (bid == 0) {
        double t = block_reduce((double)a[tid] + (double)a[tid + 1024], s16);
        if (tid == 0) ws->a_sum = t;
    } else if (bid == 1) {
        double t = block_reduce((double)b[tid] + (double)b[tid + 1024], s16);
        if (tid == 0) ws->b_sum = t;
    }

    const int i = r0 + rloc;
    const float4* c4 = (const float4*)(C + (size_t)i * N);
    double s = 0.0, s2 = 0.0;
    #pragma unroll 4
    for (int j4 = cgrp; j4 < N / 4; j4 += 128) {
        float4 c = c4[j4];
        const double ex = (double)expf(-10.0f * c.x);
        const double ey = (double)expf(-10.0f * c.y);
        const double ez = (double)expf(-10.0f * c.z);
        const double ew = (double)expf(-10.0f * c.w);
        s  += ex + ey + ez + ew;
        s2 += ex * ex + ey * ey + ez * ez + ew * ew;
    }
    for (int off = 32; off; off >>= 1) s += __shfl_xor(s, off, 64);
    __syncthreads();                     // s16 free (block_reduce readers done)
    if (lane == 0) s16[tid >> 6] = s;    // 2 waves per row
    __syncthreads();
    if (tid < RPB) ws->rowSum[r0 + tid] = s16[2 * tid] + s16[2 * tid + 1];
    if (tid == 0) {
        double bs = 0.0;
        #pragma unroll
        for (int w = 0; w < 16; ++w) bs += s16[w];
        ws->bandSum[bid] = bs;
    }
    const double bs2 = block_reduce(s2, s16);
    if (tid == 0) ws->s2Band[bid] = bs2;
}

// ---- K2: iter-0 row scaling (U), column partials T/G/H -> [col][srcblk] ----
__global__ void __launch_bounds__(NTHR)
k2_rowscale_colpart(const float* __restrict__ C, const float* __restrict__ a,
                    Ws* __restrict__ ws)
{
    __shared__ double s16[16];
    __shared__ double sU[RPB];
    const int tid = threadIdx.x, bid = blockIdx.x;
    const int r0 = bid * RPB;

    const double k0sum = block_reduce((tid < NBLK) ? ws->bandSum[tid] : 0.0, s16);
    const double W0 = D_MASS / k0sum;

    if (tid < RPB) {
        const int i = r0 + tid;
        double r = ((double)a[i] / ws->a_sum) / (W0 * ws->rowSum[i]);
        if (r > 1.0) r = 1.0;
        sU[tid] = r;
        ws->U[i] = (float)r;
    }
    __syncthreads();

    double ub[RPB], ub2[RPB];
    #pragma unroll
    for (int r = 0; r < RPB; ++r) { ub[r] = sU[r]; ub2[r] = sU[r] * sU[r]; }
    const int j0 = 2 * tid;
    double ax = 0.0, ay = 0.0, gx = 0.0, gy = 0.0, hx = 0.0, hy = 0.0;
    #pragma unroll
    for (int r = 0; r < RPB; ++r) {
        const float2 c = *(const float2*)(C + (size_t)(r0 + r) * N + j0);
        const double ex = (double)expf(-10.0f * c.x);
        const double ey = (double)expf(-10.0f * c.y);
        ax += ex * ub[r];            ay += ey * ub[r];
        gx += ex * ex * ub[r];       gy += ey * ey * ub[r];
        hx += ex * ex * ub2[r];      hy += ey * ey * ub2[r];
    }
    ws->partialT[(size_t)j0 * NBLK + bid]       = (float)ax;
    ws->partialT[(size_t)(j0 + 1) * NBLK + bid] = (float)ay;
    ws->partialG[(size_t)j0 * NBLK + bid]       = (float)gx;
    ws->partialG[(size_t)(j0 + 1) * NBLK + bid] = (float)gy;
    ws->partialH[(size_t)j0 * NBLK + bid]       = (float)hx;
    ws->partialH[(size_t)(j0 + 1) * NBLK + bid] = (float)hy;
}

// ---- K3: reduce T/G/H (coalesced), col scaling, V, dot + err partials ----
__global__ void __launch_bounds__(256)
k3_colscale(const float* __restrict__ b, Ws* __restrict__ ws)
{
    __shared__ double s4[4];
    __shared__ double sT[RPB], sG[RPB], sH[RPB];
    __shared__ double sD[RPB], sA[RPB], sB[RPB];
    const int tid = threadIdx.x, bid = blockIdx.x;

    double v = (double)ws->bandSum[tid];     // 256 values, one per thread
    for (int off = 32; off; off >>= 1) v += __shfl_xor(v, off, 64);
    if ((tid & 63) == 0) s4[tid >> 6] = v;
    __syncthreads();
    const double W0 = D_MASS / (s4[0] + s4[1] + s4[2] + s4[3]);

    const int jj = tid >> 5, p = tid & 31;   // 32 threads per column
    const int j = bid * RPB + jj;
    double t = 0.0, g = 0.0, h = 0.0;
    #pragma unroll
    for (int q = 0; q < 8; ++q) {
        const size_t idx = (size_t)j * NBLK + p + 32 * q;
        t += (double)ws->partialT[idx];
        g += (double)ws->partialG[idx];
        h += (double)ws->partialH[idx];
    }
    #pragma unroll
    for (int off = 16; off; off >>= 1) {
        t += __shfl_xor(t, off, 64);
        g += __shfl_xor(g, off, 64);
        h += __shfl_xor(h, off, 64);
    }
    if (p == 0) { sT[jj] = t; sG[jj] = g; sH[jj] = h; }
    __syncthreads();

    if (tid < RPB) {
        const int jc = bid * RPB + tid;
        const double Tj = sT[tid];
        double cf = ((double)b[jc] / ws->b_sum) / (W0 * Tj);   // Vq = 1
        if (cf > 1.0) cf = 1.0;
        ws->V[jc] = (float)cf;
        sD[tid] = Tj * cf;
        sA[tid] = sG[tid] * cf;          // V_j * G_j
        sB[tid] = sH[tid] * cf * cf;     // V_j^2 * H_j
    }
    __syncthreads();
    if (tid == 0) {
        double d = 0.0, ea = 0.0, eb = 0.0;
        #pragma unroll
        for (int q = 0; q < RPB; ++q) { d += sD[q]; ea += sA[q]; eb += sB[q]; }
        ws->dotParts[bid] = d;
        ws->errAParts[bid] = ea;
        ws->errBParts[bid] = eb;
    }
}

// ---- K4: redundant closed-form decision; converged -> write output.
//      Not converged (never on this data): block 0 runs serial fallback. ----
__global__ void __launch_bounds__(NTHR)
k4_decide_out(const float* __restrict__ C, const float* __restrict__ a,
              const float* __restrict__ b, float* __restrict__ K,
              Ws* __restrict__ ws)
{
    __shared__ double s16[16];
    const int tid = threadIdx.x, bid = blockIdx.x;
    const int r0 = bid * RPB, rloc = tid >> 7, cgrp = tid & 127;

    // redundant scalar reduces (bitwise-identical across blocks)
    const double sd    = block_reduce((tid < NBLK) ? ws->dotParts[tid]  : 0.0, s16);
    const double errAs = block_reduce((tid < NBLK) ? ws->errAParts[tid] : 0.0, s16);
    const double errBs = block_reduce((tid < NBLK) ? ws->errBParts[tid] : 0.0, s16);
    const double s2tot = block_reduce((tid < NBLK) ? ws->s2Band[tid]    : 0.0, s16);
    const double k0sum = block_reduce((tid < NBLK) ? ws->bandSum[tid]   : 0.0, s16);
    const double W0 = D_MASS / k0sum;
    const double Wn = D_MASS / sd;
    const double err2 = W0 * W0 * s2tot - 2.0 * W0 * Wn * errAs + Wn * Wn * errBs;

    if (sqrt(err2) <= D_TOL) {
        // ---- fast path: converged at iter 0; write output band ----
        const int i = r0 + rloc;
        const double unw = Wn * (double)ws->U[i];
        const float4* c4  = (const float4*)(C + (size_t)i * N);
        const float4* vn4 = (const float4*)ws->V;
        float4* k4p = (float4*)(K + (size_t)i * N);
        #pragma unroll 4
        for (int j4 = cgrp; j4 < N / 4; j4 += 128) {
            float4 c = c4[j4], vn = vn4[j4];
            float4 kn;
            kn.x = (float)(unw * (double)expf(-10.0f * c.x) * (double)vn.x);
            kn.y = (float)(unw * (double)expf(-10.0f * c.y) * (double)vn.y);
            kn.z = (float)(unw * (double)expf(-10.0f * c.z) * (double)vn.z);
            kn.w = (float)(unw * (double)expf(-10.0f * c.w) * (double)vn.w);
            k4p[j4] = kn;
        }
        return;
    }

    // ======== fallback: block 0 runs the exact algorithm serially ========
    if (bid != 0) return;
    const double a_sum = ws->a_sum, b_sum = ws->b_sum;
    double W = Wn;                           // state after iter-0 mass scale

    for (int i = tid; i < N; i += NTHR) {    // seed state from iter 0
        ws->Ud[i]  = (double)ws->U[i];
        ws->rpD[i] = ws->Ud[i];              // row_prev = r (Uq was 1)
        ws->Vd[i]  = (double)ws->V[i];
        ws->cpD[i] = ws->Vd[i];
        ws->UpD[i] = 1.0; ws->VpD[i] = 1.0;
    }
    __syncthreads();

    double Wp = 0.0;
    bool done = false;
    for (int cpt = 1; cpt < NITER && !done; ++cpt) {
        const bool erriter = (cpt % 10) == 0;
        if (erriter) {
            Wp = W;
            for (int i = tid; i < N; i += NTHR) {
                ws->UpD[i] = ws->Ud[i]; ws->VpD[i] = ws->Vd[i];
            }
        }
        __syncthreads();

        // row scaling
        for (int i = tid; i < N; i += NTHR) {
            const float* crow = C + (size_t)i * N;
            double s = 0.0;
            for (int j = 0; j < N; ++j)
                s += (double)expf(-10.0f * crow[j]) * ws->Vd[j];
            const double Uq = ws->Ud[i] / ws->rpD[i];
            double r = ((double)a[i] / a_sum) / (Uq * W * s);
            if (r > 1.0) r = 1.0;
            ws->Ud[i] = Uq * r; ws->rpD[i] = r;
        }
        __syncthreads();

        // col scaling + dot
        double dloc = 0.0;
        for (int j = tid; j < N; j += NTHR) {
            double t = 0.0;
            for (int i = 0; i < N; ++i)
                t += (double)expf(-10.0f * C[(size_t)i * N + j]) * ws->Ud[i];
            const double Vq = ws->Vd[j] / ws->cpD[j];
            double cf = ((double)b[j] / b_sum) / (Vq * W * t);
            if (cf > 1.0) cf = 1.0;
            const double Vn = Vq * cf;
            ws->Vd[j] = Vn; ws->cpD[j] = cf;
            dloc += t * Vn;
        }
        const double sdl = block_reduce(dloc, s16);
        W = D_MASS / sdl;                    // post-mass-scale W of this iter

        if (erriter) {
            double e2 = 0.0;
            for (int i = tid; i < N; i += NTHR) {
                const float* crow = C + (size_t)i * N;
                const double up = Wp * ws->UpD[i];
                const double un = W  * ws->Ud[i];
                for (int j = 0; j < N; ++j) {
                    const double k0 = (double)expf(-10.0f * crow[j]);
                    const double d = k0 * (up * ws->VpD[j] - un * ws->Vd[j]);
                    e2 += d * d;
                }
            }
            const double te = block_reduce(e2, s16);
            done = (sqrt(te) <= D_TOL);
        }
        __syncthreads();
    }

    // final output from current state
    for (int i = tid; i < N; i += NTHR) {
        const float* crow = C + (size_t)i * N;
        float* krow = K + (size_t)i * N;
        const double uw = W * ws->Ud[i];
        for (int j = 0; j < N; ++j)
            krow[j] = (float)(uw * (double)expf(-10.0f * crow[j]) * ws->Vd[j]);
    }
}

extern "C" void kernel_launch(void* const* d_in, const int* in_sizes, int n_in,
                              void* d_out, int out_size, void* d_ws, size_t ws_size,
                              hipStream_t stream) {
    const float* C = (const float*)d_in[0];
    const float* a = (const float*)d_in[1];
    const float* b = (const float*)d_in[2];
    float* K = (float*)d_out;
    Ws*    w = (Ws*)d_ws;

    k1_sums<<<NBLK, NTHR, 0, stream>>>(C, a, b, w);
    k2_rowscale_colpart<<<NBLK, NTHR, 0, stream>>>(C, a, w);
    k3_colscale<<<NBLK, 256, 0, stream>>>(b, w);
    k4_decide_out<<<NBLK, NTHR, 0, stream>>>(C, a, b, K, w);
}